// Round 3
// 99.948 us; speedup vs baseline: 1.0777x; 1.0777x over previous
//
#include <hip/hip_runtime.h>
#include <math.h>

#define SEQ 512
#define HID 256
#define NH 8
#define DH 32
#define PI_F 3.14159265358979323846f
#define SCALE_F 0.17677669529663687f  /* 1/sqrt(32) */
#define LOG2E_F 1.4426950408889634f

// ws layout (float offsets) — partials eliminated, only activation planes + ctx
#define OFF_OMEGA 0
#define OFF_AMP   131072
#define OFF_PHASE 262144
#define OFF_V     393216
#define OFF_CTX   524288

__device__ __forceinline__ float sigmoidf_(float x) { return 1.f / (1.f + expf(-x)); }

// ---------------- fused full-K GEMM + bias + activation epilogue ----------------
// out[r,c] = act( sum_{k=0..255} A[r,k] * W[c,k] + bias[c] )
// Tile 32 rows x 64 cols, K looped in 4 chunks of 64 (single block owns full K,
// so no partial write/re-read and no reduce kernel).
// LDS: A natural [r][k] stride 68 (2-way banks), W transposed [k][c^swz] with
// XOR-4 swizzle so both transpose-write and b128 compute-read are <=2-way.
// mode: 0=Q(omega), 1=K(amp), 2=V(v+phase), 3=out-projection(+bo -> outp)
__global__ __launch_bounds__(256) void gemm_fused(
    const float* __restrict__ A,
    const float* __restrict__ W0, const float* __restrict__ W1,
    const float* __restrict__ W2,
    const float* __restrict__ bq, const float* __restrict__ bk,
    const float* __restrict__ bv, const float* __restrict__ bo,
    float* __restrict__ ws, float* __restrict__ outp, int mode_base)
{
    const int mode = mode_base + blockIdx.y;
    const float* W    = (mode == 1) ? W1 : (mode == 2) ? W2 : W0;
    const float* bias = (mode == 0) ? bq : (mode == 1) ? bk : (mode == 2) ? bv : bo;

    const int bx = blockIdx.x;
    const int ct = bx & 3;
    const int rt = bx >> 2;
    const int r0 = rt * 32, c0 = ct * 64;

    __shared__ float xs[32 * 68];
    __shared__ float wts[64 * 64];

    const int tid = threadIdx.x;
    const int rg = tid >> 4, cg = tid & 15;

    float acc[2][4];
#pragma unroll
    for (int i = 0; i < 2; i++)
#pragma unroll
        for (int j = 0; j < 4; j++) acc[i][j] = 0.f;

    for (int kc = 0; kc < 4; kc++) {
        const int k0 = kc * 64;
#pragma unroll
        for (int it = 0; it < 4; it++) {
            int idx = tid + it * 256;
            int rr = idx >> 4, f4 = idx & 15;          // 16 lanes: same rr, f4=0..15
            float4 wv = *(const float4*)(W + (c0 + rr) * HID + k0 + 4 * f4);
            int cw = rr ^ ((f4 & 7) << 2);             // swizzle on col index
            wts[(4 * f4 + 0) * 64 + cw] = wv.x;
            wts[(4 * f4 + 1) * 64 + cw] = wv.y;
            wts[(4 * f4 + 2) * 64 + cw] = wv.z;
            wts[(4 * f4 + 3) * 64 + cw] = wv.w;
            if (it < 2) {                              // A tile: only 32 rows
                float4 av = *(const float4*)(A + (r0 + rr) * HID + k0 + 4 * f4);
                *(float4*)&xs[rr * 68 + 4 * f4] = av;  // b128 write, 2-way banks
            }
        }
        __syncthreads();

#pragma unroll
        for (int g = 0; g < 16; g++) {
            float xfa[2][4], wfa[4][4];
#pragma unroll
            for (int i = 0; i < 2; i++) {
                float4 xv = *(const float4*)&xs[(2 * rg + i) * 68 + 4 * g];
                xfa[i][0] = xv.x; xfa[i][1] = xv.y; xfa[i][2] = xv.z; xfa[i][3] = xv.w;
            }
            const int sw = (g & 7) << 2;
#pragma unroll
            for (int m = 0; m < 4; m++) {
                float4 wv = *(const float4*)&wts[(4 * g + m) * 64 + ((4 * cg) ^ sw)];
                wfa[m][0] = wv.x; wfa[m][1] = wv.y; wfa[m][2] = wv.z; wfa[m][3] = wv.w;
            }
#pragma unroll
            for (int m = 0; m < 4; m++)
#pragma unroll
                for (int i = 0; i < 2; i++)
#pragma unroll
                    for (int j = 0; j < 4; j++)
                        acc[i][j] = fmaf(xfa[i][m], wfa[m][j], acc[i][j]);
        }
        __syncthreads();
    }

    // epilogue: bias + activation, write final planes (no partials)
    float4 b4 = *(const float4*)&bias[c0 + 4 * cg];
#pragma unroll
    for (int i = 0; i < 2; i++) {
        const int r = r0 + 2 * rg + i;
        const int o = r * HID + c0 + 4 * cg;
        float s0 = acc[i][0] + b4.x;
        float s1 = acc[i][1] + b4.y;
        float s2 = acc[i][2] + b4.z;
        float s3 = acc[i][3] + b4.w;
        if (mode == 0) {
            float4 t;
            t.x = PI_F * sigmoidf_(s0); t.y = PI_F * sigmoidf_(s1);
            t.z = PI_F * sigmoidf_(s2); t.w = PI_F * sigmoidf_(s3);
            *(float4*)&ws[OFF_OMEGA + o] = t;
        } else if (mode == 1) {
            float4 t;
            t.x = sigmoidf_(s0); t.y = sigmoidf_(s1);
            t.z = sigmoidf_(s2); t.w = sigmoidf_(s3);
            *(float4*)&ws[OFF_AMP + o] = t;
        } else if (mode == 2) {
            float4 t; t.x = s0; t.y = s1; t.z = s2; t.w = s3;
            *(float4*)&ws[OFF_V + o] = t;
            float4 p;
            p.x = PI_F * tanhf(s0); p.y = PI_F * tanhf(s1);
            p.z = PI_F * tanhf(s2); p.w = PI_F * tanhf(s3);
            *(float4*)&ws[OFF_PHASE + o] = p;
        } else {
            float4 t; t.x = s0; t.y = s1; t.z = s2; t.w = s3;
            *(float4*)&outp[o] = t;
        }
    }
}

// ---------------- wave-interference attention ----------------
// thread = (il = tid>>5, d = tid&31); grid (SEQ/8, NH). v in natural [j][col]
// layout -> one 128B txn per wave per j.
// p_j = aL*cos(theta0 - j*w) advanced with a Chebyshev 2-term recurrence per
// 4-chain (step -4w): p_next = 2cos(4w)*p_cur - p_prev  -> 1 FMA per key
// (vs 4 ops/key for the rotation pair), exact recurrence so only additive
// roundoff (~128*eps on a |p|<=0.26 signal). hw exp2 per key.
__global__ __launch_bounds__(256) void wave_attn(const float* __restrict__ ws,
                                                 float* __restrict__ ctx)
{
    const int h  = blockIdx.y;
    const int il = threadIdx.x >> 5;
    const int d  = threadIdx.x & 31;
    const int i  = blockIdx.x * 8 + il;
    const int col = h * DH + d;

    const float w  = ws[OFF_OMEGA + i * HID + col];
    const float aL = ws[OFF_AMP + i * HID + col] * (SCALE_F * LOG2E_F);
    const float ph = ws[OFF_PHASE + i * HID + col];
    const float* vcol = ws + OFF_V + col;

    float sw_, cw;
    sincosf(w, &sw_, &cw);
    float c2 = cw * cw - sw_ * sw_, s2 = 2.f * sw_ * cw;
    float c4 = c2 * c2 - s2 * s2;

    float th0 = fmaf(w, (float)i, ph);      // angle at j=0
    float c_, s_;
    sincosf(th0, &s_, &c_);

    // seed j=0..3 (pPrev) and j=4..7 (pCur) via 8 exact rotation steps of -w
    float pPrev[4], pCur[4];
#pragma unroll
    for (int k = 0; k < 4; k++) {
        pPrev[k] = aL * c_;
        float nc = c_ * cw + s_ * sw_;
        float ns = s_ * cw - c_ * sw_;
        c_ = nc; s_ = ns;
    }
#pragma unroll
    for (int k = 0; k < 4; k++) {
        pCur[k] = aL * c_;
        float nc = c_ * cw + s_ * sw_;
        float ns = s_ * cw - c_ * sw_;
        c_ = nc; s_ = ns;
    }
    const float C2 = 2.f * c4;              // Chebyshev multiplier, step -4w

    float den[4], num[4];
#pragma unroll
    for (int k = 0; k < 4; k++) { den[k] = 0.f; num[k] = 0.f; }

#pragma unroll 4
    for (int t = 0; t < SEQ / 4; t++) {
        float v0 = vcol[(4 * t + 0) * HID];
        float v1 = vcol[(4 * t + 1) * HID];
        float v2v = vcol[(4 * t + 2) * HID];
        float v3 = vcol[(4 * t + 3) * HID];
        float e0 = __builtin_amdgcn_exp2f(pPrev[0]);
        float e1 = __builtin_amdgcn_exp2f(pPrev[1]);
        float e2 = __builtin_amdgcn_exp2f(pPrev[2]);
        float e3 = __builtin_amdgcn_exp2f(pPrev[3]);
        den[0] += e0; den[1] += e1; den[2] += e2; den[3] += e3;
        num[0] = fmaf(e0, v0, num[0]);
        num[1] = fmaf(e1, v1, num[1]);
        num[2] = fmaf(e2, v2v, num[2]);
        num[3] = fmaf(e3, v3, num[3]);
#pragma unroll
        for (int k = 0; k < 4; k++) {       // advance each chain by -4w: 1 FMA
            float nx = fmaf(C2, pCur[k], -pPrev[k]);
            pPrev[k] = pCur[k]; pCur[k] = nx;
        }
    }
    float denom = (den[0] + den[1]) + (den[2] + den[3]);
    float numer = (num[0] + num[1]) + (num[2] + num[3]);
    ctx[i * HID + col] = numer / denom;
}

extern "C" void kernel_launch(void* const* d_in, const int* in_sizes, int n_in,
                              void* d_out, int out_size, void* d_ws, size_t ws_size,
                              hipStream_t stream) {
    const float* x  = (const float*)d_in[0];
    const float* wq = (const float*)d_in[1];
    const float* bq = (const float*)d_in[2];
    const float* wk = (const float*)d_in[3];
    const float* bk = (const float*)d_in[4];
    const float* wv = (const float*)d_in[5];
    const float* bv = (const float*)d_in[6];
    const float* wo = (const float*)d_in[7];
    const float* bo = (const float*)d_in[8];

    float* ws = (float*)d_ws;

    // 1) QKV projections, full-K, bias+activation fused (192 blocks)
    hipLaunchKernelGGL(gemm_fused, dim3(64, 3), dim3(256), 0, stream,
                       x, wq, wk, wv, bq, bk, bv, bo, ws, (float*)d_out, 0);
    // 2) wave-interference attention (512 blocks)
    hipLaunchKernelGGL(wave_attn, dim3(SEQ / 8, NH), dim3(256), 0, stream,
                       ws, ws + OFF_CTX);
    // 3) output projection, full-K, +bo fused (64 blocks)
    hipLaunchKernelGGL(gemm_fused, dim3(64, 1), dim3(256), 0, stream,
                       ws + OFF_CTX, wo, wo, wo, bq, bk, bv, bo, ws,
                       (float*)d_out, 3);
}